// Round 2
// baseline (247.631 us; speedup 1.0000x reference)
//
#include <hip/hip_runtime.h>
#include <math.h>

#define N_NODES 8192
#define DEG 32
#define EMBED 256
#define NHEAD 8
#define HDIM 32

// C[M][256] = X @ W^T + b   (X: M x 256 row-major, W: 256 x 256 row-major)
// BM=BN=64, BK=32, 256 threads, 4x4 outputs/thread, f32.
__global__ __launch_bounds__(256) void gemm_xwt(const float* __restrict__ X,
                                                const float* __restrict__ W,
                                                const float* __restrict__ b,
                                                float* __restrict__ C) {
    __shared__ float As[64][33];
    __shared__ float Bs[64][33];
    const int t  = threadIdx.x;
    const int bm = blockIdx.y * 64;
    const int bn = blockIdx.x * 64;
    const int tr = t >> 4;   // 0..15
    const int tc = t & 15;   // 0..15
    float acc[4][4] = {{0.f, 0.f, 0.f, 0.f}, {0.f, 0.f, 0.f, 0.f},
                       {0.f, 0.f, 0.f, 0.f}, {0.f, 0.f, 0.f, 0.f}};
    for (int k0 = 0; k0 < EMBED; k0 += 32) {
        // Stage 64x32 tiles of X and W (float4 loads, coalesced).
#pragma unroll
        for (int r = 0; r < 2; ++r) {
            const int idx = r * 256 + t;      // 0..511 float4 slots
            const int row = idx >> 3;         // 0..63
            const int c4  = (idx & 7) * 4;    // 0,4,...,28
            const float4 va = *reinterpret_cast<const float4*>(&X[(bm + row) * EMBED + k0 + c4]);
            const float4 vb = *reinterpret_cast<const float4*>(&W[(bn + row) * EMBED + k0 + c4]);
            As[row][c4 + 0] = va.x; As[row][c4 + 1] = va.y;
            As[row][c4 + 2] = va.z; As[row][c4 + 3] = va.w;
            Bs[row][c4 + 0] = vb.x; Bs[row][c4 + 1] = vb.y;
            Bs[row][c4 + 2] = vb.z; Bs[row][c4 + 3] = vb.w;
        }
        __syncthreads();
#pragma unroll
        for (int kk = 0; kk < 32; ++kk) {
            float a[4], w[4];
#pragma unroll
            for (int i = 0; i < 4; ++i) a[i] = As[tr * 4 + i][kk];
#pragma unroll
            for (int j = 0; j < 4; ++j) w[j] = Bs[tc * 4 + j][kk];
#pragma unroll
            for (int i = 0; i < 4; ++i)
#pragma unroll
                for (int j = 0; j < 4; ++j)
                    acc[i][j] = fmaf(a[i], w[j], acc[i][j]);
        }
        __syncthreads();
    }
#pragma unroll
    for (int i = 0; i < 4; ++i) {
        const int row = bm + tr * 4 + i;
#pragma unroll
        for (int j = 0; j < 4; ++j) {
            const int col = bn + tc * 4 + j;
            C[row * EMBED + col] = acc[i][j] + b[col];
        }
    }
}

// One block per destination node. 256 threads = 8 heads x 32 dims.
// dst of edge e is e/DEG (dst = repeat(arange(N), DEG)), so node n's edges
// are e = n*DEG .. n*DEG+31 contiguously; src read from edge_index[:,0].
// Every gathered K/V element is used exactly once per block -> no LDS
// staging; direct coalesced reads, L2-resident (K,V are 8 MB each).
__global__ __launch_bounds__(256) void edge_attn(const float* __restrict__ Q,
                                                 const float* __restrict__ K,
                                                 const float* __restrict__ V,
                                                 const int* __restrict__ edge_index,
                                                 float* __restrict__ out) {
    const int n = blockIdx.x;
    const int t = threadIdx.x;   // t = h*32 + d
    __shared__ int s_src[DEG];
    if (t < DEG) s_src[t] = edge_index[(n * DEG + t) * 2];  // src column
    __syncthreads();

    const float q = Q[n * EMBED + t];
    float sim[DEG];
#pragma unroll
    for (int j = 0; j < DEG; ++j) {
        float p = q * K[s_src[j] * EMBED + t];
        // reduce across the 32 dims (masks <=16 stay within 32-lane halves)
        p += __shfl_xor(p, 1);
        p += __shfl_xor(p, 2);
        p += __shfl_xor(p, 4);
        p += __shfl_xor(p, 8);
        p += __shfl_xor(p, 16);
        sim[j] = p * 0.17677669529663687f;  // 1/sqrt(32)
    }
    float m = sim[0];
#pragma unroll
    for (int j = 1; j < DEG; ++j) m = fmaxf(m, sim[j]);
    float den = 0.f;
#pragma unroll
    for (int j = 0; j < DEG; ++j) {
        sim[j] = __expf(sim[j] - m);
        den += sim[j];
    }
    const float inv = 1.f / den;
    float o = 0.f;
#pragma unroll
    for (int j = 0; j < DEG; ++j) o += sim[j] * V[s_src[j] * EMBED + t];
    out[n * EMBED + t] = o * inv;
}

extern "C" void kernel_launch(void* const* d_in, const int* in_sizes, int n_in,
                              void* d_out, int out_size, void* d_ws, size_t ws_size,
                              hipStream_t stream) {
    const float* feats      = (const float*)d_in[0];
    const int*   edge_index = (const int*)d_in[1];
    // d_in[2] = edge_attr (unused by the reference math)
    const float* Wq = (const float*)d_in[3];
    const float* bq = (const float*)d_in[4];
    const float* Wk = (const float*)d_in[5];
    const float* bk = (const float*)d_in[6];
    const float* Wv = (const float*)d_in[7];
    const float* bv = (const float*)d_in[8];
    const float* Wo = (const float*)d_in[9];
    const float* bo = (const float*)d_in[10];
    float* out = (float*)d_out;

    float* Q   = (float*)d_ws;
    float* K   = Q + (size_t)N_NODES * EMBED;
    float* V   = K + (size_t)N_NODES * EMBED;
    float* att = V + (size_t)N_NODES * EMBED;

    dim3 g(EMBED / 64, N_NODES / 64);
    gemm_xwt<<<g, 256, 0, stream>>>(feats, Wq, bq, Q);
    gemm_xwt<<<g, 256, 0, stream>>>(feats, Wk, bk, K);
    gemm_xwt<<<g, 256, 0, stream>>>(feats, Wv, bv, V);
    edge_attn<<<N_NODES, 256, 0, stream>>>(Q, K, V, edge_index, att);
    gemm_xwt<<<g, 256, 0, stream>>>(att, Wo, bo, out);
}

// Round 6
// 128.415 us; speedup vs baseline: 1.9284x; 1.9284x over previous
//
#include <hip/hip_runtime.h>
#include <hip/hip_bf16.h>
#include <math.h>

#define N_NODES 8192
#define DEG 32
#define EMBED 256
#define NHEAD 8
#define HDIM 32

typedef __attribute__((ext_vector_type(8))) short bf16x8;
typedef __attribute__((ext_vector_type(8))) unsigned short ushort8;
typedef __attribute__((ext_vector_type(4))) float f32x4;

__device__ __forceinline__ unsigned short f2bf(float x) {
    union { float f; unsigned int u; } c; c.f = x;
    unsigned int r = (c.u + 0x7FFFu + ((c.u >> 16) & 1u)) >> 16;
    return (unsigned short)r;
}
__device__ __forceinline__ float bf2f(unsigned short u) {
    union { unsigned int u; float f; } c; c.u = ((unsigned int)u) << 16;
    return c.f;
}

// Merged conversion: blocks 0..2047 feats->bf16; 2048..2303 weights; 2304 biases.
__global__ __launch_bounds__(256) void convert_all(
        const float* __restrict__ feats,
        const float* __restrict__ Wq, const float* __restrict__ Wk,
        const float* __restrict__ Wv, const float* __restrict__ Wo,
        const float* __restrict__ bq, const float* __restrict__ bk,
        const float* __restrict__ bv,
        unsigned short* __restrict__ Xb,
        unsigned short* __restrict__ Wqkvb, unsigned short* __restrict__ Wob,
        float* __restrict__ bias768) {
    const int b = blockIdx.x;
    if (b < 2048) {
        const int i = (b * 256 + threadIdx.x) * 4;
        const float4 v = *reinterpret_cast<const float4*>(&feats[i]);
        ushort4 r;
        r.x = f2bf(v.x); r.y = f2bf(v.y); r.z = f2bf(v.z); r.w = f2bf(v.w);
        *reinterpret_cast<ushort4*>(&Xb[i]) = r;
    } else if (b < 2304) {
        const int bb  = b - 2048;
        const int seg = bb >> 6;           // 0..3
        const int i = (bb & 63) * 1024 + threadIdx.x * 4;
        const float* src = (seg == 0) ? Wq : (seg == 1) ? Wk : (seg == 2) ? Wv : Wo;
        const float4 v = *reinterpret_cast<const float4*>(&src[i]);
        ushort4 r;
        r.x = f2bf(v.x); r.y = f2bf(v.y); r.z = f2bf(v.z); r.w = f2bf(v.w);
        if (seg < 3) *reinterpret_cast<ushort4*>(&Wqkvb[seg * 65536 + i]) = r;
        else         *reinterpret_cast<ushort4*>(&Wob[i]) = r;
    } else {
        const int i = threadIdx.x;
        bias768[i]       = bq[i];
        bias768[256 + i] = bk[i];
        bias768[512 + i] = bv[i];
    }
}

// C[M][N] = Xb @ Wb^T + bias, bf16 MFMA 16x16x32. BM=BN=64, BK=64 (4 K-iters,
// LDS 18.4 KB -> ~7 blocks/CU resident for latency hiding). 4 waves, each a
// 32x32 quadrant (2x2 frags). LDS rows padded to 72 ushorts (144 B = +4
// banks/row -> 2-way conflicts = free per m136).
// IS_QKV: N=768; cols<256 -> Qf f32, cols>=256 -> KVb bf16 [8192][512].
template <int IS_QKV>
__global__ __launch_bounds__(256) void gemm_mfma(const unsigned short* __restrict__ X,
                                                 const unsigned short* __restrict__ W,
                                                 const float* __restrict__ bias,
                                                 float* __restrict__ outF,
                                                 unsigned short* __restrict__ outKV) {
    __shared__ unsigned short Xs[64][72];
    __shared__ unsigned short Ws[64][72];
    const int t    = threadIdx.x;
    const int bm   = blockIdx.y * 64;
    const int bn   = blockIdx.x * 64;
    const int lane = t & 63;
    const int wv   = t >> 6;
    const int wm   = (wv >> 1) * 32;
    const int wn   = (wv & 1) * 32;
    const int fr   = lane & 15;     // fragment row/col
    const int ksel = lane >> 4;     // 0..3 k-group

    f32x4 acc[2][2] = {};

    for (int k0 = 0; k0 < 256; k0 += 64) {
        // stage 64x64 of X and W (8 chunks of 16B per row)
#pragma unroll
        for (int i = 0; i < 2; ++i) {
            const int id  = i * 256 + t;  // 0..511
            const int row = id >> 3;      // 0..63
            const int c   = id & 7;       // 0..7
            *reinterpret_cast<uint4*>(&Xs[row][c * 8]) =
                *reinterpret_cast<const uint4*>(&X[(bm + row) * 256 + k0 + c * 8]);
            *reinterpret_cast<uint4*>(&Ws[row][c * 8]) =
                *reinterpret_cast<const uint4*>(&W[(bn + row) * 256 + k0 + c * 8]);
        }
        __syncthreads();
#pragma unroll
        for (int kf = 0; kf < 2; ++kf) {
            const int ck = (kf * 4 + ksel) * 8;
            bf16x8 a0 = *reinterpret_cast<const bf16x8*>(&Xs[wm + fr][ck]);
            bf16x8 a1 = *reinterpret_cast<const bf16x8*>(&Xs[wm + 16 + fr][ck]);
            bf16x8 b0 = *reinterpret_cast<const bf16x8*>(&Ws[wn + fr][ck]);
            bf16x8 b1 = *reinterpret_cast<const bf16x8*>(&Ws[wn + 16 + fr][ck]);
            acc[0][0] = __builtin_amdgcn_mfma_f32_16x16x32_bf16(a0, b0, acc[0][0], 0, 0, 0);
            acc[0][1] = __builtin_amdgcn_mfma_f32_16x16x32_bf16(a0, b1, acc[0][1], 0, 0, 0);
            acc[1][0] = __builtin_amdgcn_mfma_f32_16x16x32_bf16(a1, b0, acc[1][0], 0, 0, 0);
            acc[1][1] = __builtin_amdgcn_mfma_f32_16x16x32_bf16(a1, b1, acc[1][1], 0, 0, 0);
        }
        __syncthreads();
    }

    // C/D frag: col = lane&15, row = (lane>>4)*4 + reg  [verified m89/m91]
#pragma unroll
    for (int mf = 0; mf < 2; ++mf)
#pragma unroll
        for (int nf = 0; nf < 2; ++nf)
#pragma unroll
            for (int reg = 0; reg < 4; ++reg) {
                const int row = bm + wm + mf * 16 + ksel * 4 + reg;
                const int col = bn + wn + nf * 16 + fr;
                const float v = acc[mf][nf][reg] + bias[col];
                if (IS_QKV) {
                    if (col < 256) outF[row * 256 + col] = v;
                    else           outKV[row * 512 + (col - 256)] = f2bf(v);
                } else {
                    outF[row * 256 + col] = v;
                }
            }
}

// One block per dst node; 256 threads. ILP-restructured:
//  QK phase: thread (h,j) computes the FULL 32-dim dot in-thread from 4
//    independent 16B K gathers (no per-edge shuffle chains).
//  Softmax: one 5-shfl pass within 32-lane half-waves (t=h*32+j keeps each
//    head inside one half of a 64-lane wave; xor masks <=16 stay inside).
//  PV phase: thread (h,d): 32 independent scalar gathers; for fixed j all
//    256 threads read one contiguous 512B V-row segment (fully coalesced).
__global__ __launch_bounds__(256) void edge_attn(const float* __restrict__ Qf,
                                                 const unsigned short* __restrict__ KVb,
                                                 const int* __restrict__ edge_index,
                                                 unsigned short* __restrict__ attb) {
    const int n = blockIdx.x;
    const int t = threadIdx.x;
    const int h = t >> 5;     // head
    const int j = t & 31;     // edge slot (QK) / dim (PV)
    __shared__ int   s_src[DEG];
    __shared__ float Qs[EMBED];
    __shared__ float wls[NHEAD][DEG];

    if (t < DEG) s_src[t] = edge_index[(n * DEG + t) * 2];
    Qs[t] = Qf[n * EMBED + t];
    __syncthreads();

    // --- QK: dot(Q[h,:], K[src_j][h,:]) fully in-thread ---
    const unsigned short* kp = &KVb[(size_t)s_src[j] * 512 + h * HDIM];
    float s = 0.f;
#pragma unroll
    for (int c = 0; c < 4; ++c) {
        const ushort8 kv = *reinterpret_cast<const ushort8*>(&kp[c * 8]);
        const float4 q0 = *reinterpret_cast<const float4*>(&Qs[h * HDIM + c * 8]);
        const float4 q1 = *reinterpret_cast<const float4*>(&Qs[h * HDIM + c * 8 + 4]);
        s = fmaf(bf2f(kv[0]), q0.x, s);
        s = fmaf(bf2f(kv[1]), q0.y, s);
        s = fmaf(bf2f(kv[2]), q0.z, s);
        s = fmaf(bf2f(kv[3]), q0.w, s);
        s = fmaf(bf2f(kv[4]), q1.x, s);
        s = fmaf(bf2f(kv[5]), q1.y, s);
        s = fmaf(bf2f(kv[6]), q1.z, s);
        s = fmaf(bf2f(kv[7]), q1.w, s);
    }
    s *= 0.17677669529663687f;  // 1/sqrt(32)

    // --- softmax over the 32 edge slots (one butterfly pass) ---
    float m = s;
    m = fmaxf(m, __shfl_xor(m, 1));
    m = fmaxf(m, __shfl_xor(m, 2));
    m = fmaxf(m, __shfl_xor(m, 4));
    m = fmaxf(m, __shfl_xor(m, 8));
    m = fmaxf(m, __shfl_xor(m, 16));
    const float p = __expf(s - m);
    float den = p;
    den += __shfl_xor(den, 1);
    den += __shfl_xor(den, 2);
    den += __shfl_xor(den, 4);
    den += __shfl_xor(den, 8);
    den += __shfl_xor(den, 16);
    wls[h][j] = p / den;
    __syncthreads();

    // --- PV: out[h,d] = sum_j w[h,j] * V[src_j][h,d] ---
    float o = 0.f;
#pragma unroll
    for (int jj = 0; jj < DEG; ++jj) {
        o = fmaf(wls[h][jj],
                 bf2f(KVb[(size_t)s_src[jj] * 512 + 256 + h * HDIM + j]), o);
    }
    attb[n * EMBED + t] = f2bf(o);
}

extern "C" void kernel_launch(void* const* d_in, const int* in_sizes, int n_in,
                              void* d_out, int out_size, void* d_ws, size_t ws_size,
                              hipStream_t stream) {
    const float* feats      = (const float*)d_in[0];
    const int*   edge_index = (const int*)d_in[1];
    const float* Wq = (const float*)d_in[3];
    const float* bq = (const float*)d_in[4];
    const float* Wk = (const float*)d_in[5];
    const float* bk = (const float*)d_in[6];
    const float* Wv = (const float*)d_in[7];
    const float* bv = (const float*)d_in[8];
    const float* Wo = (const float*)d_in[9];
    const float* bo = (const float*)d_in[10];
    float* out = (float*)d_out;

    // workspace layout (all 16B-aligned)
    unsigned short* Xb     = (unsigned short*)d_ws;                 // 8192*256 bf16 (4 MB)
    unsigned short* Wqkvb  = Xb + 8192 * 256;                       // 768*256
    unsigned short* Wob    = Wqkvb + 768 * 256;                     // 256*256
    float*          bias768= (float*)(Wob + 256 * 256);             // 768 f32 (+pad)
    float*          Qf     = (float*)((char*)bias768 + 4096);       // 8192*256 f32 (8 MB)
    unsigned short* KVb    = (unsigned short*)(Qf + 8192 * 256);    // 8192*512 bf16 (8 MB)
    unsigned short* attb   = KVb + (size_t)8192 * 512;              // 8192*256 bf16 (4 MB)

    convert_all<<<2305, 256, 0, stream>>>(feats, Wq, Wk, Wv, Wo, bq, bk, bv,
                                          Xb, Wqkvb, Wob, bias768);
    gemm_mfma<1><<<dim3(12, 128), 256, 0, stream>>>(Xb, Wqkvb, bias768, Qf, KVb);
    edge_attn<<<N_NODES, 256, 0, stream>>>(Qf, KVb, edge_index, attb);
    gemm_mfma<0><<<dim3(4, 128), 256, 0, stream>>>(attb, Wob, bo, out, nullptr);
}